// Round 1
// baseline (111.854 us; speedup 1.0000x reference)
//
#include <hip/hip_runtime.h>
#include <math.h>

// Problem geometry (fixed by reference): B=4, C=3, D=H=W=64.
#define VOXB 262144              // 64^3 voxels per batch
#define NVOX 1048576             // 4 * VOXB
#define NPART 1024               // partial blocks per accumulator (256 x-blocks * 4 batches)
#define NACC 14
#define BIGF 1.0e8f

// ---------------------------------------------------------------------------
// Kernel 1: init EDT buffers. d2pos = (t==1)?0:BIG ; d2neg = (t==1)?BIG:0
// ---------------------------------------------------------------------------
__global__ __launch_bounds__(256) void init_edt(const int* __restrict__ tg,
                                                float* __restrict__ dp,
                                                float* __restrict__ dn) {
    int i = blockIdx.x * 256 + threadIdx.x;     // i indexes int4 groups
    int4 t = reinterpret_cast<const int4*>(tg)[i];
    float4 p, n;
    p.x = (t.x == 1) ? 0.f : BIGF;  n.x = (t.x == 1) ? BIGF : 0.f;
    p.y = (t.y == 1) ? 0.f : BIGF;  n.y = (t.y == 1) ? BIGF : 0.f;
    p.z = (t.z == 1) ? 0.f : BIGF;  n.z = (t.z == 1) ? BIGF : 0.f;
    p.w = (t.w == 1) ? 0.f : BIGF;  n.w = (t.w == 1) ? BIGF : 0.f;
    reinterpret_cast<float4*>(dp)[i] = p;
    reinterpret_cast<float4*>(dn)[i] = n;
}

// ---------------------------------------------------------------------------
// Kernel 2: one separable EDT pass along an axis with element stride STRIDE.
// Each 64-lane wave owns one 64-element line; line value lives in a register;
// lower envelope realized as min_j (shfl(v,j) + (i-j)^2).
// blockDim = 256 (4 waves = 4 lines); blockIdx.y in {0,1} selects pos/neg
// buffer (they are contiguous in workspace).
// ---------------------------------------------------------------------------
template <int STRIDE>
__global__ __launch_bounds__(256) void edt_pass(float* __restrict__ base) {
    float* d = base + blockIdx.y * NVOX;
    int w    = threadIdx.x >> 6;
    int lane = threadIdx.x & 63;
    int line = blockIdx.x * 4 + w;          // [0, 16384)
    int outer = line / STRIDE;              // compile-time pow2 -> shift
    int inner = line - outer * STRIDE;
    int addr  = outer * (64 * STRIDE) + inner + lane * STRIDE;
    float v = d[addr];
    float m = v;
#pragma unroll
    for (int j = 0; j < 64; ++j) {
        float vj = __shfl(v, j, 64);
        float dx = (float)(lane - j);
        m = fminf(m, vj + dx * dx);
    }
    d[addr] = m;
}

// ---------------------------------------------------------------------------
// Kernel 3: fused pointwise pass + two-stage reduction (stage 1).
// Accumulators (indices):
//  0 focal_sum   = sum alpha_t*(1-p_t)^2*log_p_t
//  1..3 inter_c  = sum p_c * (t==c)
//  4..6 psum_c   = sum p_c
//  7..9 tsum_c   = sum (t==c)         (tsum_1 per-batch doubles as gsum_b)
//  10 sknum      = sum p1*skel
//  11 skden      = sum skel
//  12 predsum_b  = sum p1             (per-batch)
//  13 termsum_b  = sum p1*(sqrt(d2p)-sqrt(d2n))  (per-batch)
// Grid: (256, 4=batch), block 256, 4 voxels/thread (vectorized loads).
// ---------------------------------------------------------------------------
__device__ __forceinline__ void vox_accum(float l0, float l1, float l2,
                                          int t, int s, float d2p, float d2n,
                                          float* acc) {
    float m  = fmaxf(l0, fmaxf(l1, l2));
    float e0 = __expf(l0 - m), e1 = __expf(l1 - m), e2 = __expf(l2 - m);
    float sum = e0 + e1 + e2;
    float inv = 1.0f / sum;
    float p0 = e0 * inv, p1 = e1 * inv, p2 = e2 * inv;
    float logs = __logf(sum);
    float pt, lpt, alpha;
    if (t == 0)      { pt = p0; lpt = l0 - m - logs; alpha = 0.3f; }
    else if (t == 1) { pt = p1; lpt = l1 - m - logs; alpha = 3.0f; }
    else             { pt = p2; lpt = l2 - m - logs; alpha = 0.3f; }
    float om = 1.0f - pt;
    acc[0] += alpha * om * om * lpt;
    acc[1] += (t == 0) ? p0 : 0.f;
    acc[2] += (t == 1) ? p1 : 0.f;
    acc[3] += (t == 2) ? p2 : 0.f;
    acc[4] += p0; acc[5] += p1; acc[6] += p2;
    acc[7] += (t == 0) ? 1.f : 0.f;
    acc[8] += (t == 1) ? 1.f : 0.f;
    acc[9] += (t == 2) ? 1.f : 0.f;
    float fs = (float)s;
    acc[10] += p1 * fs;
    acc[11] += fs;
    float sd = sqrtf(d2p) - sqrtf(d2n);
    acc[12] += p1;
    acc[13] += p1 * sd;
}

__global__ __launch_bounds__(256) void reduce_main(
        const float* __restrict__ logits, const int* __restrict__ targets,
        const int* __restrict__ skel, const float* __restrict__ d2pos,
        const float* __restrict__ d2neg, float* __restrict__ partials) {
    int b = blockIdx.y;
    int vbase = blockIdx.x * 1024 + threadIdx.x * 4;   // within-batch voxel
    int gv = b * VOXB + vbase;
    const float* lg = logits + (size_t)b * 3 * VOXB + vbase;
    float4 L0 = *reinterpret_cast<const float4*>(lg);
    float4 L1 = *reinterpret_cast<const float4*>(lg + VOXB);
    float4 L2 = *reinterpret_cast<const float4*>(lg + 2 * VOXB);
    int4   tg = *reinterpret_cast<const int4*>(targets + gv);
    int4   sk = *reinterpret_cast<const int4*>(skel + gv);
    float4 dp = *reinterpret_cast<const float4*>(d2pos + gv);
    float4 dn = *reinterpret_cast<const float4*>(d2neg + gv);

    float acc[NACC];
#pragma unroll
    for (int k = 0; k < NACC; ++k) acc[k] = 0.f;
    vox_accum(L0.x, L1.x, L2.x, tg.x, sk.x, dp.x, dn.x, acc);
    vox_accum(L0.y, L1.y, L2.y, tg.y, sk.y, dp.y, dn.y, acc);
    vox_accum(L0.z, L1.z, L2.z, tg.z, sk.z, dp.z, dn.z, acc);
    vox_accum(L0.w, L1.w, L2.w, tg.w, sk.w, dp.w, dn.w, acc);

    __shared__ float red[4][NACC];
    int w = threadIdx.x >> 6, lane = threadIdx.x & 63;
#pragma unroll
    for (int k = 0; k < NACC; ++k) {
        float v = acc[k];
#pragma unroll
        for (int off = 32; off; off >>= 1) v += __shfl_down(v, off, 64);
        if (lane == 0) red[w][k] = v;
    }
    __syncthreads();
    if (threadIdx.x < NACC) {
        float v = red[0][threadIdx.x] + red[1][threadIdx.x] +
                  red[2][threadIdx.x] + red[3][threadIdx.x];
        partials[threadIdx.x * NPART + b * 256 + blockIdx.x] = v;
    }
}

// ---------------------------------------------------------------------------
// Kernel 4: final reduction (single block, 256 threads = 4 waves) + scalar
// loss assembly in f64. Wave w reduces batch b=w's 256 partials per value,
// preserving per-batch sums; thread 0 combines.
// ---------------------------------------------------------------------------
__global__ __launch_bounds__(256) void final_reduce(
        const float* __restrict__ partials, float* __restrict__ out) {
    __shared__ float sb[NACC][4];
    int w = threadIdx.x >> 6, lane = threadIdx.x & 63;
#pragma unroll
    for (int k = 0; k < NACC; ++k) {
        const float* p = partials + k * NPART + w * 256;
        float v = p[lane] + p[lane + 64] + p[lane + 128] + p[lane + 192];
#pragma unroll
        for (int off = 32; off; off >>= 1) v += __shfl_down(v, off, 64);
        if (lane == 0) sb[k][w] = v;
    }
    __syncthreads();
    if (threadIdx.x == 0) {
        double S[NACC];
#pragma unroll
        for (int k = 0; k < NACC; ++k)
            S[k] = (double)sb[k][0] + sb[k][1] + sb[k][2] + sb[k][3];
        const double W[3] = {0.3, 3.0, 0.3};
        double focal = -S[0] / (double)NVOX;
        double dice = 0.0;
        for (int c = 0; c < 3; ++c)
            dice += W[c] * (1.0 - (2.0 * S[1 + c] + 1.0) /
                                  (S[4 + c] + S[7 + c] + 1.0));
        double lfd = focal + dice / 3.6;
        double lsk = 1.0 - (S[10] + 1.0) / (S[11] + 1.0);
        double lb = 0.0;
        for (int b = 0; b < 4; ++b) {
            double gs = sb[8][b];          // per-batch count of targets==1
            double ps = sb[12][b];         // per-batch sum of pred
            double tm = sb[13][b];         // per-batch sum of pred*signed
            double per;
            if (gs == 0.0)            per = ps / (double)VOXB;
            else if (gs == (double)VOXB) per = 1.0 - ps / (double)VOXB;
            else                      per = tm / (double)VOXB;
            lb += per;
        }
        lb *= 0.25;
        double total = 0.3 * lfd + 0.3 * lsk + 0.2 * lb;
        out[0] = (float)total;
        out[1] = (float)lfd;
        out[2] = (float)lsk;
        out[3] = (float)lb;
    }
}

// ---------------------------------------------------------------------------
extern "C" void kernel_launch(void* const* d_in, const int* in_sizes, int n_in,
                              void* d_out, int out_size, void* d_ws, size_t ws_size,
                              hipStream_t stream) {
    const float* logits  = (const float*)d_in[0];
    const int*   targets = (const int*)d_in[1];   // jax x64 disabled -> int32
    const int*   skel    = (const int*)d_in[2];
    float* d2pos    = (float*)d_ws;               // NVOX floats
    float* d2neg    = d2pos + NVOX;               // NVOX floats
    float* partials = d2neg + NVOX;               // NACC * NPART floats
    float* out = (float*)d_out;

    init_edt<<<NVOX / 4 / 256, 256, 0, stream>>>(targets, d2pos, d2neg);

    dim3 gl(16384 / 4, 2);   // 4 lines per block, y = pos/neg buffer
    edt_pass<1>   <<<gl, 256, 0, stream>>>(d2pos);   // axis W
    edt_pass<64>  <<<gl, 256, 0, stream>>>(d2pos);   // axis H
    edt_pass<4096><<<gl, 256, 0, stream>>>(d2pos);   // axis D

    reduce_main<<<dim3(256, 4), 256, 0, stream>>>(logits, targets, skel,
                                                  d2pos, d2neg, partials);
    final_reduce<<<1, 256, 0, stream>>>(partials, out);
}

// Round 2
// 33.093 us; speedup vs baseline: 3.3800x; 3.3800x over previous
//
#include <hip/hip_runtime.h>
#include <math.h>

// Geometry fixed by reference: B=4, C=3, D=H=W=64.
#define VOXB 262144              // 64^3
#define NVOX 1048576             // 4 * VOXB
#define NACC 14
#define BIGF 1.0e8f
#define PITCH 65                 // padded LDS pitch: bank=(w+j)%32, 2-way = free

// ---------------------------------------------------------------------------
// nearest^2 distance to a set bit in a 64-bit line mask, for lane position i.
// ---------------------------------------------------------------------------
__device__ __forceinline__ float nearest2(unsigned long long m, int i) {
    if (m == 0ull) return BIGF;
    unsigned long long right = m >> i;            // bits j >= i
    unsigned long long left  = m << (63 - i);     // bits j <= i
    int dr = right ? __builtin_ctzll(right) : 1000;
    int dl = left  ? __builtin_clzll(left)  : 1000;
    int d  = (dr < dl) ? dr : dl;
    return (float)(d * d);
}

// ---------------------------------------------------------------------------
// Kernel A: per (b,d) plane [h][w]. Axis-W EDT via ballot bit-scan (O(1)/vox),
// then axis-H EDT via transposed-LDS radius spiral with uniform early exit.
// Writes d2pos/d2neg (partial EDT over W,H).
// ---------------------------------------------------------------------------
__global__ __launch_bounds__(512) void edt_wh(const int* __restrict__ targets,
                                              float* __restrict__ d2pos,
                                              float* __restrict__ d2neg) {
    __shared__ float Tp[64 * PITCH];   // Tp[w][j=h]
    __shared__ float Tn[64 * PITCH];
    int pb   = blockIdx.x * 4096;      // (b*64+d)*4096
    int wv   = threadIdx.x >> 6;       // wave 0..7
    int lane = threadIdx.x & 63;       // = w

    // W phase: each wave owns 8 rows h; one ballot per row.
    for (int r = 0; r < 8; ++r) {
        int h = wv * 8 + r;
        int tv = targets[pb + h * 64 + lane];
        unsigned long long mp = __ballot(tv == 1);
        unsigned long long mn = ~mp;
        Tp[lane * PITCH + h] = nearest2(mp, lane);
        Tn[lane * PITCH + h] = nearest2(mn, lane);
    }
    __syncthreads();

    // H phase: output row h; lane=w reads its own column (conflict-free).
    for (int rt = 0; rt < 8; ++rt) {
        int h = wv * 8 + rt;
        float mp = Tp[lane * PITCH + h];
        float mn = Tn[lane * PITCH + h];
        for (int r = 1; r < 64; ++r) {
            int jl = h - r; if (jl < 0) jl = 0;
            int jr = h + r; if (jr > 63) jr = 63;
            float rr = (float)(r * r);
            mp = fminf(mp, fminf(Tp[lane * PITCH + jl], Tp[lane * PITCH + jr]) + rr);
            mn = fminf(mn, fminf(Tn[lane * PITCH + jl], Tn[lane * PITCH + jr]) + rr);
            float thr = (float)((r + 1) * (r + 1));
            if (__all((mp <= thr) && (mn <= thr))) break;  // remaining terms >= (r+1)^2
        }
        d2pos[pb + h * 64 + lane] = mp;
        d2neg[pb + h * 64 + lane] = mn;
    }
}

// ---------------------------------------------------------------------------
// Per-voxel pointwise math + accumulation (sd = signed distance, precomputed).
// ---------------------------------------------------------------------------
__device__ __forceinline__ void vox_accum(float l0, float l1, float l2,
                                          int t, int s, float sd, float* acc) {
    float m  = fmaxf(l0, fmaxf(l1, l2));
    float e0 = __expf(l0 - m), e1 = __expf(l1 - m), e2 = __expf(l2 - m);
    float sum = e0 + e1 + e2;
    float inv = 1.0f / sum;
    float p0 = e0 * inv, p1 = e1 * inv, p2 = e2 * inv;
    float logs = __logf(sum);
    float pt, lpt, alpha;
    if (t == 0)      { pt = p0; lpt = l0 - m - logs; alpha = 0.3f; }
    else if (t == 1) { pt = p1; lpt = l1 - m - logs; alpha = 3.0f; }
    else             { pt = p2; lpt = l2 - m - logs; alpha = 0.3f; }
    float om = 1.0f - pt;
    acc[0] += alpha * om * om * lpt;
    acc[1] += (t == 0) ? p0 : 0.f;
    acc[2] += (t == 1) ? p1 : 0.f;
    acc[3] += (t == 2) ? p2 : 0.f;
    acc[4] += p0; acc[5] += p1; acc[6] += p2;
    acc[7] += (t == 0) ? 1.f : 0.f;
    acc[8] += (t == 1) ? 1.f : 0.f;
    acc[9] += (t == 2) ? 1.f : 0.f;
    float fs = (float)s;
    acc[10] += p1 * fs;
    acc[11] += fs;
    acc[12] += p1;
    acc[13] += p1 * sd;
}

// ---------------------------------------------------------------------------
// Kernel B: per (b,h) plane [d][w]. Axis-D EDT (transposed-LDS spiral), then
// fused softmax/focal/dice/skel/boundary accumulation; block partials out.
// ---------------------------------------------------------------------------
__global__ __launch_bounds__(512) void edt_d_reduce(
        const float* __restrict__ logits, const int* __restrict__ targets,
        const int* __restrict__ skel, const float* __restrict__ d2pos,
        const float* __restrict__ d2neg, float* __restrict__ partials) {
    __shared__ float Tp[64 * PITCH];   // Tp[w][j=d]
    __shared__ float Tn[64 * PITCH];
    __shared__ float red[8][NACC];
    int b = blockIdx.x >> 6, h = blockIdx.x & 63;
    int vb = b * VOXB + h * 64;
    int t = threadIdx.x;

    // Load both planes, transposing into LDS (coalesced global float4 reads).
    for (int k = 0; k < 2; ++k) {
        int f  = k * 512 + t;          // float4 group 0..1023
        int d  = f >> 4;
        int w0 = (f & 15) * 4;
        const float4 qp = *reinterpret_cast<const float4*>(d2pos + vb + d * 4096 + w0);
        const float4 qn = *reinterpret_cast<const float4*>(d2neg + vb + d * 4096 + w0);
        Tp[(w0    ) * PITCH + d] = qp.x; Tp[(w0 + 1) * PITCH + d] = qp.y;
        Tp[(w0 + 2) * PITCH + d] = qp.z; Tp[(w0 + 3) * PITCH + d] = qp.w;
        Tn[(w0    ) * PITCH + d] = qn.x; Tn[(w0 + 1) * PITCH + d] = qn.y;
        Tn[(w0 + 2) * PITCH + d] = qn.z; Tn[(w0 + 3) * PITCH + d] = qn.w;
    }
    __syncthreads();

    int wv = t >> 6, lane = t & 63;    // lane = w
    float acc[NACC];
#pragma unroll
    for (int k = 0; k < NACC; ++k) acc[k] = 0.f;

    for (int rt = 0; rt < 8; ++rt) {
        int d = wv * 8 + rt;           // output row (depth index)
        float mp = Tp[lane * PITCH + d];
        float mn = Tn[lane * PITCH + d];
        for (int r = 1; r < 64; ++r) {
            int jl = d - r; if (jl < 0) jl = 0;
            int jr = d + r; if (jr > 63) jr = 63;
            float rr = (float)(r * r);
            mp = fminf(mp, fminf(Tp[lane * PITCH + jl], Tp[lane * PITCH + jr]) + rr);
            mn = fminf(mn, fminf(Tn[lane * PITCH + jl], Tn[lane * PITCH + jr]) + rr);
            float thr = (float)((r + 1) * (r + 1));
            if (__all((mp <= thr) && (mn <= thr))) break;
        }
        float sd = sqrtf(mp) - sqrtf(mn);

        int voff = vb + d * 4096 + lane;
        int tv = targets[voff];
        int sv = skel[voff];
        int lb = b * (3 * VOXB) + d * 4096 + h * 64 + lane;
        float l0 = logits[lb];
        float l1 = logits[lb + VOXB];
        float l2 = logits[lb + 2 * VOXB];
        vox_accum(l0, l1, l2, tv, sv, sd, acc);
    }

    // wave reduce -> LDS -> block reduce -> partials[k][block]
#pragma unroll
    for (int k = 0; k < NACC; ++k) {
        float v = acc[k];
#pragma unroll
        for (int off = 32; off; off >>= 1) v += __shfl_down(v, off, 64);
        if (lane == 0) red[wv][k] = v;
    }
    __syncthreads();
    if (t < NACC) {
        float v = 0.f;
#pragma unroll
        for (int q = 0; q < 8; ++q) v += red[q][t];
        partials[t * 256 + blockIdx.x] = v;
    }
}

// ---------------------------------------------------------------------------
// Kernel C: final reduction (1 block). Wave w reduces batch w's 64 block
// partials (blocks b*64..b*64+63 belong to batch b); thread 0 assembles in f64.
// ---------------------------------------------------------------------------
__global__ __launch_bounds__(256) void final_reduce(
        const float* __restrict__ partials, float* __restrict__ out) {
    __shared__ float sb[NACC][4];
    int w = threadIdx.x >> 6, lane = threadIdx.x & 63;
#pragma unroll
    for (int k = 0; k < NACC; ++k) {
        float v = partials[k * 256 + w * 64 + lane];
#pragma unroll
        for (int off = 32; off; off >>= 1) v += __shfl_down(v, off, 64);
        if (lane == 0) sb[k][w] = v;
    }
    __syncthreads();
    if (threadIdx.x == 0) {
        double S[NACC];
#pragma unroll
        for (int k = 0; k < NACC; ++k)
            S[k] = (double)sb[k][0] + sb[k][1] + sb[k][2] + sb[k][3];
        const double W[3] = {0.3, 3.0, 0.3};
        double focal = -S[0] / (double)NVOX;
        double dice = 0.0;
        for (int c = 0; c < 3; ++c)
            dice += W[c] * (1.0 - (2.0 * S[1 + c] + 1.0) /
                                  (S[4 + c] + S[7 + c] + 1.0));
        double lfd = focal + dice / 3.6;
        double lsk = 1.0 - (S[10] + 1.0) / (S[11] + 1.0);
        double lb = 0.0;
        for (int bb = 0; bb < 4; ++bb) {
            double gs = sb[8][bb];
            double ps = sb[12][bb];
            double tm = sb[13][bb];
            double per;
            if (gs == 0.0)               per = ps / (double)VOXB;
            else if (gs == (double)VOXB) per = 1.0 - ps / (double)VOXB;
            else                         per = tm / (double)VOXB;
            lb += per;
        }
        lb *= 0.25;
        double total = 0.3 * lfd + 0.3 * lsk + 0.2 * lb;
        out[0] = (float)total;
        out[1] = (float)lfd;
        out[2] = (float)lsk;
        out[3] = (float)lb;
    }
}

// ---------------------------------------------------------------------------
extern "C" void kernel_launch(void* const* d_in, const int* in_sizes, int n_in,
                              void* d_out, int out_size, void* d_ws, size_t ws_size,
                              hipStream_t stream) {
    const float* logits  = (const float*)d_in[0];
    const int*   targets = (const int*)d_in[1];
    const int*   skel    = (const int*)d_in[2];
    float* d2pos    = (float*)d_ws;
    float* d2neg    = d2pos + NVOX;
    float* partials = d2neg + NVOX;    // NACC * 256 floats
    float* out = (float*)d_out;

    edt_wh<<<256, 512, 0, stream>>>(targets, d2pos, d2neg);
    edt_d_reduce<<<256, 512, 0, stream>>>(logits, targets, skel,
                                          d2pos, d2neg, partials);
    final_reduce<<<1, 256, 0, stream>>>(partials, out);
}